// Round 1
// baseline (274.677 us; speedup 1.0000x reference)
//
#include <hip/hip_runtime.h>
#include <hip/hip_bf16.h>

typedef __attribute__((ext_vector_type(8))) short bf16x8;
typedef __attribute__((ext_vector_type(4))) float f32x4;

__device__ __forceinline__ void async_copy16(void* lds, const void* g) {
  __builtin_amdgcn_global_load_lds(
      (const __attribute__((address_space(1))) unsigned int*)g,
      (__attribute__((address_space(3))) unsigned int*)lds,
      16, 0, 0);
}

// One wave per row: fp32 -> bf16 convert + fp32 row sum-of-squares.
__global__ void rbf_prep(const float* __restrict__ x, const float* __restrict__ y,
                         short* __restrict__ xb, short* __restrict__ yb,
                         float* __restrict__ xsq, float* __restrict__ ysq,
                         int n, int m) {
  const int gw   = (int)((blockIdx.x * blockDim.x + threadIdx.x) >> 6);
  const int lane = threadIdx.x & 63;
  if (gw >= n + m) return;
  const float* src;
  short* dst;
  float* nrm;
  int row;
  if (gw < n) { src = x; dst = xb; nrm = xsq; row = gw; }
  else        { src = y; dst = yb; nrm = ysq; row = gw - n; }
  // 128 floats per row, 2 per lane
  const float2 v = ((const float2*)(src + (size_t)row * 128))[lane];
  float ss = v.x * v.x + v.y * v.y;
  #pragma unroll
  for (int off = 32; off > 0; off >>= 1) ss += __shfl_down(ss, off, 64);
  __hip_bfloat16 bx = __float2bfloat16(v.x);
  __hip_bfloat16 by = __float2bfloat16(v.y);
  short2 o;
  o.x = *(short*)&bx;
  o.y = *(short*)&by;
  ((short2*)(dst + (size_t)row * 128))[lane] = o;
  if (lane == 0) nrm[row] = ss;
}

// 128x128 output tile per block; 4 waves in 2x2, each wave 64x64 via 4x4
// mfma_f32_16x16x32_bf16. Full K=128 staged once (2 x 32KB LDS).
// LDS layout: [row][chunk-slot], slot = chunk ^ (row & 15) (XOR swizzle applied
// on the global SOURCE address, since global_load_lds dest is uniform+lane*16).
__global__ __launch_bounds__(256, 2)
void rbf_gemm(const short* __restrict__ xb, const short* __restrict__ yb,
              const float* __restrict__ xsq, const float* __restrict__ ysq,
              const float* __restrict__ gptr, float* __restrict__ out,
              int mcols) {
  __shared__ __align__(16) short xs[128 * 128];
  __shared__ __align__(16) short ys[128 * 128];
  const int tid  = threadIdx.x;
  const int lane = tid & 63;
  const int wv   = tid >> 6;
  const int bn = blockIdx.x, bm = blockIdx.y;
  const int wm = wv >> 1, wn = wv & 1;
  const int quad = lane >> 4, l15 = lane & 15;

  // ---- stage both tiles (global rows are contiguous 256B; coalesced) ----
  {
    const int r0 = lane >> 4;   // 0..3 within a 1KB segment (4 rows)
    const int s  = lane & 15;   // 16B chunk slot within row
    const size_t xrow0 = (size_t)bm * 128;
    const size_t yrow0 = (size_t)bn * 128;
    #pragma unroll
    for (int ii = 0; ii < 8; ++ii) {
      const int seg = wv + ii * 4;       // 32 segments of 1KB per tile
      const int r = seg * 4 + r0;
      const int c = s ^ (r & 15);        // source chunk for this slot
      async_copy16(xs + seg * 512, xb + (xrow0 + r) * 128 + c * 8);
      async_copy16(ys + seg * 512, yb + (yrow0 + r) * 128 + c * 8);
    }
  }

  f32x4 acc[4][4];
  #pragma unroll
  for (int i = 0; i < 4; ++i)
    #pragma unroll
    for (int j = 0; j < 4; ++j)
      acc[i][j] = (f32x4){0.f, 0.f, 0.f, 0.f};

  __syncthreads();  // compiler emits vmcnt(0) drain before s_barrier

  // ---- K loop: 4 steps of K=32 ----
  #pragma unroll
  for (int kk = 0; kk < 4; ++kk) {
    const int c = kk * 4 + quad;   // 16B chunk index along K
    const int s = c ^ l15;         // un-swizzle (row&15 == l15 for all tiles)
    bf16x8 af[4], bfv[4];
    #pragma unroll
    for (int t = 0; t < 4; ++t) {
      af[t]  = *(const bf16x8*)(xs + (wm * 64 + t * 16 + l15) * 128 + s * 8);
      bfv[t] = *(const bf16x8*)(ys + (wn * 64 + t * 16 + l15) * 128 + s * 8);
    }
    #pragma unroll
    for (int i = 0; i < 4; ++i)
      #pragma unroll
      for (int j = 0; j < 4; ++j)
        acc[i][j] = __builtin_amdgcn_mfma_f32_16x16x32_bf16(af[i], bfv[j], acc[i][j], 0, 0, 0);
  }

  // ---- epilogue: sq = xsq + ysq - 2*dot, clamp, exp ----
  const float ng2 = -gptr[0] * 1.4426950408889634f;  // -gamma * log2(e)
  float ysqc[4];
  const int col0 = bn * 128 + wn * 64 + l15;
  #pragma unroll
  for (int j = 0; j < 4; ++j) ysqc[j] = ysq[col0 + j * 16];
  const int row0 = bm * 128 + wm * 64 + quad * 4;  // D row = quad*4 + reg
  #pragma unroll
  for (int i = 0; i < 4; ++i) {
    #pragma unroll
    for (int r = 0; r < 4; ++r) {
      const int rg = row0 + i * 16 + r;
      const float xr = xsq[rg];
      float* orow = out + (size_t)rg * (size_t)mcols + col0;
      #pragma unroll
      for (int j = 0; j < 4; ++j) {
        float sq = xr + ysqc[j] - 2.0f * acc[i][j][r];
        sq = fmaxf(sq, 0.0f);
        orow[j * 16] = exp2f(ng2 * sq);
      }
    }
  }
}

extern "C" void kernel_launch(void* const* d_in, const int* in_sizes, int n_in,
                              void* d_out, int out_size, void* d_ws, size_t ws_size,
                              hipStream_t stream) {
  const float* x     = (const float*)d_in[0];
  const float* y     = (const float*)d_in[1];
  const float* gamma = (const float*)d_in[2];
  float* out = (float*)d_out;
  const int d = 128;
  const int n = in_sizes[0] / d;   // 8192
  const int m = in_sizes[1] / d;   // 8192

  // workspace: xb (n*128 bf16) | yb (m*128 bf16) | xsq (n f32) | ysq (m f32)
  short* xb  = (short*)d_ws;
  short* yb  = xb + (size_t)n * d;
  float* xsq = (float*)(yb + (size_t)m * d);
  float* ysq = xsq + n;

  const int waves  = n + m;
  const int blocks = (waves * 64 + 255) / 256;
  rbf_prep<<<blocks, 256, 0, stream>>>(x, y, xb, yb, xsq, ysq, n, m);

  dim3 grid(m / 128, n / 128);
  rbf_gemm<<<grid, 256, 0, stream>>>(xb, yb, xsq, ysq, gamma, out, m);
}

// Round 2
// 274.449 us; speedup vs baseline: 1.0008x; 1.0008x over previous
//
#include <hip/hip_runtime.h>
#include <hip/hip_bf16.h>

typedef __attribute__((ext_vector_type(8))) short bf16x8;
typedef __attribute__((ext_vector_type(4))) float f32x4;

__device__ __forceinline__ void async_copy16(void* lds, const void* g) {
  __builtin_amdgcn_global_load_lds(
      (const __attribute__((address_space(1))) unsigned int*)g,
      (__attribute__((address_space(3))) unsigned int*)lds,
      16, 0, 0);
}

// Two rows per wave: fp32 -> bf16 convert (float4/short4) + fp32 row norms.
__global__ __launch_bounds__(256)
void rbf_prep(const float* __restrict__ x, const float* __restrict__ y,
              short* __restrict__ xb, short* __restrict__ yb,
              float* __restrict__ xsq, float* __restrict__ ysq,
              int n, int m) {
  const int gw   = (int)((blockIdx.x * blockDim.x + threadIdx.x) >> 6);
  const int lane = threadIdx.x & 63;
  const int half = lane >> 5;   // which of the wave's 2 rows
  const int l32  = lane & 31;   // 32 lanes x float4 = 128 floats = 1 row
  const int rid  = gw * 2 + half;
  if (rid >= n + m) return;
  const float* src;
  short* dst;
  float* nrm;
  int row;
  if (rid < n) { src = x; dst = xb; nrm = xsq; row = rid; }
  else         { src = y; dst = yb; nrm = ysq; row = rid - n; }
  const float4 v = ((const float4*)(src + (size_t)row * 128))[l32];
  float ss = v.x * v.x + v.y * v.y + v.z * v.z + v.w * v.w;
  #pragma unroll
  for (int off = 16; off > 0; off >>= 1) ss += __shfl_down(ss, off, 64);
  __hip_bfloat16 b0 = __float2bfloat16(v.x);
  __hip_bfloat16 b1 = __float2bfloat16(v.y);
  __hip_bfloat16 b2 = __float2bfloat16(v.z);
  __hip_bfloat16 b3 = __float2bfloat16(v.w);
  short4 o;
  o.x = *(short*)&b0; o.y = *(short*)&b1;
  o.z = *(short*)&b2; o.w = *(short*)&b3;
  ((short4*)(dst + (size_t)row * 128))[l32] = o;
  if (l32 == 0) nrm[row] = ss;
}

// 128x128 output tile per block; 4 waves in 2x2, each wave 64x64 via 4x4
// mfma_f32_16x16x32_bf16. Full K=128 staged once (2 x 32KB LDS, 2 blocks/CU).
// LDS layout: [row][chunk-slot], slot = chunk ^ (row & 15) (XOR swizzle applied
// on the global SOURCE address, since global_load_lds dest is uniform+lane*16).
__global__ __launch_bounds__(256, 2)
void rbf_gemm(const short* __restrict__ xb, const short* __restrict__ yb,
              const float* __restrict__ xsq, const float* __restrict__ ysq,
              const float* __restrict__ gptr, float* __restrict__ out,
              int mcols) {
  __shared__ __align__(16) short xs[128 * 128];
  __shared__ __align__(16) short ys[128 * 128];
  const int tid  = threadIdx.x;
  const int lane = tid & 63;
  const int wv   = tid >> 6;
  const int bn = blockIdx.x, bm = blockIdx.y;
  const int wm = wv >> 1, wn = wv & 1;
  const int quad = lane >> 4, l15 = lane & 15;

  // ---- stage both tiles (global rows are contiguous 256B; coalesced) ----
  {
    const int r0 = lane >> 4;   // 0..3 within a 1KB segment (4 rows)
    const int s  = lane & 15;   // 16B chunk slot within row
    const size_t xrow0 = (size_t)bm * 128;
    const size_t yrow0 = (size_t)bn * 128;
    #pragma unroll
    for (int ii = 0; ii < 8; ++ii) {
      const int seg = wv + ii * 4;       // 32 segments of 1KB per tile
      const int r = seg * 4 + r0;
      const int c = s ^ (r & 15);        // source chunk for this slot
      async_copy16(xs + seg * 512, xb + (xrow0 + r) * 128 + c * 8);
      async_copy16(ys + seg * 512, yb + (yrow0 + r) * 128 + c * 8);
    }
  }

  f32x4 acc[4][4];
  #pragma unroll
  for (int i = 0; i < 4; ++i)
    #pragma unroll
    for (int j = 0; j < 4; ++j)
      acc[i][j] = (f32x4){0.f, 0.f, 0.f, 0.f};

  __syncthreads();  // compiler emits vmcnt(0) drain before s_barrier

  // ---- K loop: 4 steps of K=32 ----
  #pragma unroll
  for (int kk = 0; kk < 4; ++kk) {
    const int c = kk * 4 + quad;   // 16B chunk index along K
    const int s = c ^ l15;         // un-swizzle (row&15 == l15 for all tiles)
    bf16x8 af[4], bfv[4];
    #pragma unroll
    for (int t = 0; t < 4; ++t) {
      af[t]  = *(const bf16x8*)(xs + (wm * 64 + t * 16 + l15) * 128 + s * 8);
      bfv[t] = *(const bf16x8*)(ys + (wn * 64 + t * 16 + l15) * 128 + s * 8);
    }
    #pragma unroll
    for (int i = 0; i < 4; ++i)
      #pragma unroll
      for (int j = 0; j < 4; ++j)
        acc[i][j] = __builtin_amdgcn_mfma_f32_16x16x32_bf16(af[i], bfv[j], acc[i][j], 0, 0, 0);
  }

  // ---- epilogue: sq = xsq + ysq - 2*dot, clamp, exp ----
  const float ng2 = -gptr[0] * 1.4426950408889634f;  // -gamma * log2(e)
  float ysqc[4];
  const int col0 = bn * 128 + wn * 64 + l15;
  #pragma unroll
  for (int j = 0; j < 4; ++j) ysqc[j] = ysq[col0 + j * 16];
  const int row0 = bm * 128 + wm * 64 + quad * 4;  // D row = quad*4 + reg
  #pragma unroll
  for (int i = 0; i < 4; ++i) {
    // rows row0+i*16 .. +3 are consecutive -> one float4 load of xsq
    const float4 xr4 = *(const float4*)(xsq + row0 + i * 16);
    const float xr[4] = {xr4.x, xr4.y, xr4.z, xr4.w};
    #pragma unroll
    for (int r = 0; r < 4; ++r) {
      const int rg = row0 + i * 16 + r;
      float* orow = out + (size_t)rg * (size_t)mcols + col0;
      #pragma unroll
      for (int j = 0; j < 4; ++j) {
        float sq = xr[r] + ysqc[j] - 2.0f * acc[i][j][r];
        sq = fmaxf(sq, 0.0f);
        orow[j * 16] = exp2f(ng2 * sq);
      }
    }
  }
}

extern "C" void kernel_launch(void* const* d_in, const int* in_sizes, int n_in,
                              void* d_out, int out_size, void* d_ws, size_t ws_size,
                              hipStream_t stream) {
  const float* x     = (const float*)d_in[0];
  const float* y     = (const float*)d_in[1];
  const float* gamma = (const float*)d_in[2];
  float* out = (float*)d_out;
  const int d = 128;
  const int n = in_sizes[0] / d;   // 8192
  const int m = in_sizes[1] / d;   // 8192

  // workspace: xb (n*128 bf16) | yb (m*128 bf16) | xsq (n f32) | ysq (m f32)
  short* xb  = (short*)d_ws;
  short* yb  = xb + (size_t)n * d;
  float* xsq = (float*)(yb + (size_t)m * d);
  float* ysq = xsq + n;

  const int waves  = (n + m + 1) / 2;            // 2 rows per wave
  const int blocks = (waves * 64 + 255) / 256;
  rbf_prep<<<blocks, 256, 0, stream>>>(x, y, xb, yb, xsq, ysq, n, m);

  dim3 grid(m / 128, n / 128);
  rbf_gemm<<<grid, 256, 0, stream>>>(xb, yb, xsq, ysq, gamma, out, m);
}